// Round 4
// baseline (174.604 us; speedup 1.0000x reference)
//
#include <hip/hip_runtime.h>

// Morphological dilation2d on MI355X (gfx950).
// out[b,o,h,w] = max_{c,i,j} ( x_zpad[b,c,h+i-2,w+j-2] + weight[o,c,i,j] )
// B=4, C=4, O=4, H=W=1024, K=5, PAD=2, fp32.
//
// Round-4: identical to the measured-77us kernel EXCEPT the j-max reduction is
// forced into v_max3_f32 via scalar inline asm. CDNA4 has no packed-fp32 max,
// so max3 (2 maxes/instr) is the only way to halve the reduction cost; LLVM's
// fmaxf->v_max3 combine is not guaranteed under default FP semantics. The
// 6-value reduce (5 sums + acc) is max(max3(q0,q1,q2), max3(q3,q4,acc)):
// 3 instrs instead of up to 5.

constexpr int Himg = 1024, Wimg = 1024, Cin = 4, Cout = 4, Kn = 5;
constexpr int TH = 8, TW = 128;     // output tile per 256-thread block
constexpr int LR = TH + 4;          // 12 LDS rows (halo +-2)
constexpr int LC = TW + 8;          // 136 LDS cols (halo -4..+3 for aligned b128 window reads)
constexpr int LC4 = LC / 4;         // 34 float4 chunks per row
constexpr int NW = Cout * Cin * Kn * Kn;  // 400 weights

typedef float v2f __attribute__((ext_vector_type(2)));

// weight [o][c][i][j] -> wd[c][i][o][j] = {w, w}  (duplicated pairs, 3.2 KB)
__global__ void reorg_w(const float* __restrict__ w, float* __restrict__ wd) {
  int idx = threadIdx.x;
  if (idx < NW) {
    int o  = idx / (Cin * Kn * Kn);
    int r  = idx % (Cin * Kn * Kn);
    int c  = r / (Kn * Kn);
    int r2 = r % (Kn * Kn);
    int i  = r2 / Kn, j = r2 % Kn;
    float v = w[idx];
    int d = (((c * Kn + i) * Cout + o) * Kn + j) * 2;
    wd[d + 0] = v;
    wd[d + 1] = v;
  }
}

// Forced 3-input max: one VOP3 v_max3_f32 (2 maxes per instr).
__device__ __forceinline__ float max3f(float a, float b, float c) {
  float d;
  asm("v_max3_f32 %0, %1, %2, %3" : "=v"(d) : "v"(a), "v"(b), "v"(c));
  return d;
}

template <bool DUP>
__global__ __launch_bounds__(256) void morph(const float* __restrict__ x,
                                             const float* __restrict__ wt,
                                             float* __restrict__ out) {
  __shared__ __align__(16) float xs[Cin][LR][LC];
  const int tid = threadIdx.x;
  const int tile_w0 = blockIdx.x * TW;
  const int tile_r0 = blockIdx.y * TH;
  const int b = blockIdx.z;

  // ---- stage x tile (+halo, zero pad) into LDS, float4 coalesced ----
  for (int idx = tid; idx < Cin * LR * LC4; idx += 256) {
    const int c   = idx / (LR * LC4);
    const int rem = idx - c * (LR * LC4);
    const int row = rem / LC4;
    const int ch  = rem - row * LC4;
    const int gr  = tile_r0 - 2 + row;
    const int gc  = tile_w0 - 4 + ch * 4;
    float4 v = make_float4(0.f, 0.f, 0.f, 0.f);
    if ((unsigned)gr < (unsigned)Himg) {
      const float* src = x + ((size_t)(b * Cin + c) * Himg + gr) * Wimg;
      if (gc >= 0 && gc <= Wimg - 4) {
        v = *(const float4*)(src + gc);
      } else {
        if ((unsigned)(gc + 0) < (unsigned)Wimg) v.x = src[gc + 0];
        if ((unsigned)(gc + 1) < (unsigned)Wimg) v.y = src[gc + 1];
        if ((unsigned)(gc + 2) < (unsigned)Wimg) v.z = src[gc + 2];
        if ((unsigned)(gc + 3) < (unsigned)Wimg) v.w = src[gc + 3];
      }
    }
    *(float4*)&xs[c][row][ch * 4] = v;
  }
  __syncthreads();

  const int tx = tid & 31;   // 32 thread-cols x 4 px
  const int ty = tid >> 5;   // 8 rows

  float acc[Cout][4];
#pragma unroll
  for (int o = 0; o < Cout; ++o)
#pragma unroll
    for (int p = 0; p < 4; ++p) acc[o][p] = -3.4e38f;

// Per output-channel O: 10 packed adds (v_pk_add_f32, SGPR-fed weight pairs)
// + 4 x (2 v_max3 + 1 v_max) with the acc fold inside the tree.
#define ACC_O(O, WPAIR)                                                                   \
  do {                                                                                    \
    v2f p01[5], p23[5];                                                                   \
    _Pragma("unroll") for (int j = 0; j < 5; ++j) {                                       \
      v2f wb = WPAIR;                                                                     \
      p01[j] = a2[j] + wb;                                                                \
      p23[j] = b2[j] + wb;                                                                \
    }                                                                                     \
    acc[O][0] = fmaxf(max3f(p01[0].x, p01[1].x, p01[2].x),                                \
                      max3f(p01[3].x, p01[4].x, acc[O][0]));                              \
    acc[O][1] = fmaxf(max3f(p01[0].y, p01[1].y, p01[2].y),                                \
                      max3f(p01[3].y, p01[4].y, acc[O][1]));                              \
    acc[O][2] = fmaxf(max3f(p23[0].x, p23[1].x, p23[2].x),                                \
                      max3f(p23[3].x, p23[4].x, acc[O][2]));                              \
    acc[O][3] = fmaxf(max3f(p23[0].y, p23[1].y, p23[2].y),                                \
                      max3f(p23[3].y, p23[4].y, acc[O][3]));                              \
  } while (0)

#pragma unroll 1
  for (int c = 0; c < Cin; ++c) {
#pragma unroll
    for (int i = 0; i < Kn; ++i) {
      const float* rowp = &xs[c][ty + i][tx * 4];
      float4 q0 = *(const float4*)(rowp);
      float4 q1 = *(const float4*)(rowp + 4);
      float4 q2 = *(const float4*)(rowp + 8);
      float win[12] = {q0.x, q0.y, q0.z, q0.w, q1.x, q1.y, q1.z, q1.w,
                       q2.x, q2.y, q2.z, q2.w};

      // window pairs, shared across the 4 output channels
      v2f a2[5], b2[5];
#pragma unroll
      for (int j = 0; j < 5; ++j) {
        a2[j].x = win[2 + j]; a2[j].y = win[3 + j];
        b2[j].x = win[4 + j]; b2[j].y = win[5 + j];
      }

      if (DUP) {
        // wave-uniform duplicated pairs -> SGPR pairs feeding v_pk_add_f32
        const v2f* wdp = (const v2f*)wt + ((c * Kn + i) * Cout) * Kn;
        ACC_O(0, wdp[0 * Kn + j]);
        ACC_O(1, wdp[1 * Kn + j]);
        ACC_O(2, wdp[2 * Kn + j]);
        ACC_O(3, wdp[3 * Kn + j]);
      } else {
        float wo0[5], wo1[5], wo2[5], wo3[5];
#pragma unroll
        for (int j = 0; j < Kn; ++j) {
          wo0[j] = wt[((0 * Cin + c) * Kn + i) * Kn + j];
          wo1[j] = wt[((1 * Cin + c) * Kn + i) * Kn + j];
          wo2[j] = wt[((2 * Cin + c) * Kn + i) * Kn + j];
          wo3[j] = wt[((3 * Cin + c) * Kn + i) * Kn + j];
        }
        ACC_O(0, (v2f{wo0[j], wo0[j]}));
        ACC_O(1, (v2f{wo1[j], wo1[j]}));
        ACC_O(2, (v2f{wo2[j], wo2[j]}));
        ACC_O(3, (v2f{wo3[j], wo3[j]}));
      }
    }
  }
#undef ACC_O

  // ---- epilogue: float4 stores, coalesced ----
  const int r = tile_r0 + ty;
  const int gc0 = tile_w0 + tx * 4;
#pragma unroll
  for (int o = 0; o < Cout; ++o) {
    float4 res = make_float4(acc[o][0], acc[o][1], acc[o][2], acc[o][3]);
    *(float4*)&out[((size_t)(b * Cout + o) * Himg + r) * Wimg + gc0] = res;
  }
}

extern "C" void kernel_launch(void* const* d_in, const int* in_sizes, int n_in,
                              void* d_out, int out_size, void* d_ws, size_t ws_size,
                              hipStream_t stream) {
  const float* x = (const float*)d_in[0];
  const float* w = (const float*)d_in[1];
  float* out = (float*)d_out;

  dim3 grid(Wimg / TW, Himg / TH, 4);  // (8, 128, 4)

  if (ws_size >= sizeof(float) * 2 * NW) {
    float* wd = (float*)d_ws;
    reorg_w<<<dim3(1), dim3(512), 0, stream>>>(w, wd);
    morph<true><<<grid, dim3(256), 0, stream>>>(x, wd, out);
  } else {
    morph<false><<<grid, dim3(256), 0, stream>>>(x, w, out);
  }
}

// Round 5
// 167.256 us; speedup vs baseline: 1.0439x; 1.0439x over previous
//
#include <hip/hip_runtime.h>

// Morphological dilation2d on MI355X (gfx950).
// out[b,o,h,w] = max_{c,i,j} ( x_zpad[b,c,h+i-2,w+j-2] + weight[o,c,i,j] )
// B=4, C=4, O=4, H=W=1024, K=5, PAD=2, fp32.
//
// Round-5: structural change only (no inline asm -- rounds 1/4 proved the
// compiler's selection is already optimal and asm pays a ~3-mov/node tax).
// 8 pixels per thread (tile 16x128, 16 cols x 16 rows): per-(c,i)-iteration
// fixed overhead (window marshalling, ds addressing, weight setup, loop glue,
// ~100 VALU/iter -- half the measured issue) is amortized over 2x the pixels.
// Core cost (50 pk_add + 50 max per px) is unchanged and irreducible.
// Weight path = round-3's DUP (duplicated {w,w} SGPR pairs, measured equal).

constexpr int Himg = 1024, Wimg = 1024, Cin = 4, Cout = 4, Kn = 5;
constexpr int TH = 16, TW = 128;    // output tile per 256-thread block
constexpr int PXT = 8;              // pixels per thread (contiguous)
constexpr int LR = TH + 4;          // 20 LDS rows (halo +-2)
constexpr int LC = TW + 8;          // 136 LDS cols (halo -4..+3 keeps b128 reads aligned)
constexpr int LC4 = LC / 4;         // 34 float4 chunks per row
constexpr int NW = Cout * Cin * Kn * Kn;  // 400 weights

typedef float v2f __attribute__((ext_vector_type(2)));

// weight [o][c][i][j] -> wd[c][i][o][j] = {w, w}  (duplicated pairs, 3.2 KB)
__global__ void reorg_w(const float* __restrict__ w, float* __restrict__ wd) {
  int idx = threadIdx.x;
  if (idx < NW) {
    int o  = idx / (Cin * Kn * Kn);
    int r  = idx % (Cin * Kn * Kn);
    int c  = r / (Kn * Kn);
    int r2 = r % (Kn * Kn);
    int i  = r2 / Kn, j = r2 % Kn;
    float v = w[idx];
    int d = (((c * Kn + i) * Cout + o) * Kn + j) * 2;
    wd[d + 0] = v;
    wd[d + 1] = v;
  }
}

// 5-input max folded so LLVM forms v_max3_f32.
__device__ __forceinline__ float max5(float a, float b, float c, float d, float e) {
  return fmaxf(fmaxf(a, b), fmaxf(c, fmaxf(d, e)));
}

template <bool DUP>
__global__ __launch_bounds__(256) void morph(const float* __restrict__ x,
                                             const float* __restrict__ wt,
                                             float* __restrict__ out) {
  __shared__ __align__(16) float xs[Cin][LR][LC];
  const int tid = threadIdx.x;
  const int tile_w0 = blockIdx.x * TW;
  const int tile_r0 = blockIdx.y * TH;
  const int b = blockIdx.z;

  // ---- stage x tile (+halo, zero pad) into LDS, float4 coalesced ----
  for (int idx = tid; idx < Cin * LR * LC4; idx += 256) {
    const int c   = idx / (LR * LC4);
    const int rem = idx - c * (LR * LC4);
    const int row = rem / LC4;
    const int ch  = rem - row * LC4;
    const int gr  = tile_r0 - 2 + row;
    const int gc  = tile_w0 - 4 + ch * 4;
    float4 v = make_float4(0.f, 0.f, 0.f, 0.f);
    if ((unsigned)gr < (unsigned)Himg) {
      const float* src = x + ((size_t)(b * Cin + c) * Himg + gr) * Wimg;
      if (gc >= 0 && gc <= Wimg - 4) {
        v = *(const float4*)(src + gc);
      } else {
        if ((unsigned)(gc + 0) < (unsigned)Wimg) v.x = src[gc + 0];
        if ((unsigned)(gc + 1) < (unsigned)Wimg) v.y = src[gc + 1];
        if ((unsigned)(gc + 2) < (unsigned)Wimg) v.z = src[gc + 2];
        if ((unsigned)(gc + 3) < (unsigned)Wimg) v.w = src[gc + 3];
      }
    }
    *(float4*)&xs[c][row][ch * 4] = v;
  }
  __syncthreads();

  const int tx = tid & 15;   // 16 thread-cols x 8 px = 128
  const int ty = tid >> 4;   // 16 rows

  float acc[Cout][PXT];
#pragma unroll
  for (int o = 0; o < Cout; ++o)
#pragma unroll
    for (int p = 0; p < PXT; ++p) acc[o][p] = -3.4e38f;

#pragma unroll 1
  for (int c = 0; c < Cin; ++c) {
#pragma unroll
    for (int i = 0; i < Kn; ++i) {
      // 16 window floats serve 8 px: px p reads win[p+2 .. p+6]
      const float* rowp = &xs[c][ty + i][tx * PXT];
      float4 q0 = *(const float4*)(rowp);
      float4 q1 = *(const float4*)(rowp + 4);
      float4 q2 = *(const float4*)(rowp + 8);
      float4 q3 = *(const float4*)(rowp + 12);
      float win[16] = {q0.x, q0.y, q0.z, q0.w, q1.x, q1.y, q1.z, q1.w,
                       q2.x, q2.y, q2.z, q2.w, q3.x, q3.y, q3.z, q3.w};

      // weight pairs for this (c,i)
      const v2f* wdp = DUP ? ((const v2f*)wt + (c * Kn + i) * Cout * Kn) : nullptr;
      float wsc[Cout][Kn];
      if (!DUP) {
#pragma unroll
        for (int o = 0; o < Cout; ++o)
#pragma unroll
          for (int j = 0; j < Kn; ++j)
            wsc[o][j] = wt[((o * Cin + c) * Kn + i) * Kn + j];
      }

#pragma unroll
      for (int q = 0; q < 4; ++q) {  // px pair (2q, 2q+1)
        v2f P[5];
#pragma unroll
        for (int j = 0; j < 5; ++j) {
          P[j].x = win[2 * q + 2 + j];
          P[j].y = win[2 * q + 3 + j];
        }
#pragma unroll
        for (int o = 0; o < Cout; ++o) {
          v2f s[5];
#pragma unroll
          for (int j = 0; j < 5; ++j) {
            v2f wb;
            if (DUP) wb = wdp[o * Kn + j];           // wave-uniform -> SGPR pair
            else     { wb.x = wsc[o][j]; wb.y = wsc[o][j]; }
            s[j] = P[j] + wb;                         // v_pk_add_f32
          }
          acc[o][2 * q]     = fmaxf(acc[o][2 * q],
                                    max5(s[0].x, s[1].x, s[2].x, s[3].x, s[4].x));
          acc[o][2 * q + 1] = fmaxf(acc[o][2 * q + 1],
                                    max5(s[0].y, s[1].y, s[2].y, s[3].y, s[4].y));
        }
      }
    }
  }

  // ---- epilogue: 2x float4 stores per o, coalesced ----
  const int r = tile_r0 + ty;
  const int gc0 = tile_w0 + tx * PXT;
#pragma unroll
  for (int o = 0; o < Cout; ++o) {
    float* dst = &out[((size_t)(b * Cout + o) * Himg + r) * Wimg + gc0];
    float4 r0 = make_float4(acc[o][0], acc[o][1], acc[o][2], acc[o][3]);
    float4 r1 = make_float4(acc[o][4], acc[o][5], acc[o][6], acc[o][7]);
    *(float4*)(dst)     = r0;
    *(float4*)(dst + 4) = r1;
  }
}

extern "C" void kernel_launch(void* const* d_in, const int* in_sizes, int n_in,
                              void* d_out, int out_size, void* d_ws, size_t ws_size,
                              hipStream_t stream) {
  const float* x = (const float*)d_in[0];
  const float* w = (const float*)d_in[1];
  float* out = (float*)d_out;

  dim3 grid(Wimg / TW, Himg / TH, 4);  // (8, 64, 4)

  if (ws_size >= sizeof(float) * 2 * NW) {
    float* wd = (float*)d_ws;
    reorg_w<<<dim3(1), dim3(512), 0, stream>>>(w, wd);
    morph<true><<<grid, dim3(256), 0, stream>>>(x, wd, out);
  } else {
    morph<false><<<grid, dim3(256), 0, stream>>>(x, w, out);
  }
}

// Round 6
// 155.794 us; speedup vs baseline: 1.1207x; 1.0736x over previous
//
#include <hip/hip_runtime.h>

// Morphological dilation2d on MI355X (gfx950).
// out[b,o,h,w] = max_{c,i,j} ( x_zpad[b,c,h+i-2,w+j-2] + weight[o,c,i,j] )
// B=4, C=4, O=4, H=W=1024, K=5, PAD=2, fp32.
//
// Round-6: forensics showed ws_size < 1.6KB -- the workspace DUP path never
// ran; every measured kernel built weight splats {w,w} with ~40 v_mov per
// (c,i) iter (~20% of VALU issue). Fix without workspace: a __device__ global
// scratch holds duplicated pairs wdup[c][i][o][j] = {w,w}, written by a tiny
// setup kernel (same stream -> visibility guaranteed at kernel boundary).
// morph reads them as wave-uniform aligned 8B loads -> s_load_dwordx2 -> SGPR
// pair consumed directly by v_pk_add_f32 (VOP3P allows one 64-bit scalar
// operand). Hot loop otherwise bit-identical to the measured-77.5us round-3
// fallback. No inline asm (rounds 1/4 proved asm pays a ~3-mov/node tax).

constexpr int Himg = 1024, Wimg = 1024, Cin = 4, Cout = 4, Kn = 5;
constexpr int TH = 8, TW = 128;     // output tile per 256-thread block
constexpr int LR = TH + 4;          // 12 LDS rows (halo +-2)
constexpr int LC = TW + 8;          // 136 LDS cols (halo -4..+3 for aligned b128 window reads)
constexpr int LC4 = LC / 4;         // 34 float4 chunks per row
constexpr int NW = Cout * Cin * Kn * Kn;  // 400 weights

typedef float v2f __attribute__((ext_vector_type(2)));

// Device-global scratch: duplicated weight pairs, [c][i][o][j] = {w, w}. 3.2 KB.
__device__ __align__(16) v2f wdup[Cin * Kn * Cout * Kn];

// weight [o][c][i][j] -> wdup[c][i][o][j] = {w, w}
__global__ void reorg_w(const float* __restrict__ w) {
  int idx = threadIdx.x;
  if (idx < NW) {
    int o  = idx / (Cin * Kn * Kn);
    int r  = idx % (Cin * Kn * Kn);
    int c  = r / (Kn * Kn);
    int r2 = r % (Kn * Kn);
    int i  = r2 / Kn, j = r2 % Kn;
    float v = w[idx];
    v2f p; p.x = v; p.y = v;
    wdup[((c * Kn + i) * Cout + o) * Kn + j] = p;
  }
}

// 5-input max folded so LLVM forms v_max3_f32.
__device__ __forceinline__ float max5(float a, float b, float c, float d, float e) {
  return fmaxf(fmaxf(a, b), fmaxf(c, fmaxf(d, e)));
}

__global__ __launch_bounds__(256) void morph(const float* __restrict__ x,
                                             float* __restrict__ out) {
  __shared__ __align__(16) float xs[Cin][LR][LC];
  const int tid = threadIdx.x;
  const int tile_w0 = blockIdx.x * TW;
  const int tile_r0 = blockIdx.y * TH;
  const int b = blockIdx.z;

  // ---- stage x tile (+halo, zero pad) into LDS, float4 coalesced ----
  for (int idx = tid; idx < Cin * LR * LC4; idx += 256) {
    const int c   = idx / (LR * LC4);
    const int rem = idx - c * (LR * LC4);
    const int row = rem / LC4;
    const int ch  = rem - row * LC4;
    const int gr  = tile_r0 - 2 + row;
    const int gc  = tile_w0 - 4 + ch * 4;
    float4 v = make_float4(0.f, 0.f, 0.f, 0.f);
    if ((unsigned)gr < (unsigned)Himg) {
      const float* src = x + ((size_t)(b * Cin + c) * Himg + gr) * Wimg;
      if (gc >= 0 && gc <= Wimg - 4) {
        v = *(const float4*)(src + gc);
      } else {
        if ((unsigned)(gc + 0) < (unsigned)Wimg) v.x = src[gc + 0];
        if ((unsigned)(gc + 1) < (unsigned)Wimg) v.y = src[gc + 1];
        if ((unsigned)(gc + 2) < (unsigned)Wimg) v.z = src[gc + 2];
        if ((unsigned)(gc + 3) < (unsigned)Wimg) v.w = src[gc + 3];
      }
    }
    *(float4*)&xs[c][row][ch * 4] = v;
  }
  __syncthreads();

  const int tx = tid & 31;   // 32 thread-cols x 4 px
  const int ty = tid >> 5;   // 8 rows

  float acc[Cout][4];
#pragma unroll
  for (int o = 0; o < Cout; ++o)
#pragma unroll
    for (int p = 0; p < 4; ++p) acc[o][p] = -3.4e38f;

// Per output-channel O: 10 packed adds (v_pk_add_f32, SGPR-pair weight operand)
// + 4 x (max5 tree + acc fold).
#define ACC_O(O)                                                                          \
  do {                                                                                    \
    v2f p01[5], p23[5];                                                                   \
    _Pragma("unroll") for (int j = 0; j < 5; ++j) {                                       \
      v2f wb = wdp[(O) * Kn + j];                                                         \
      p01[j] = a2[j] + wb;                                                                \
      p23[j] = b2[j] + wb;                                                                \
    }                                                                                     \
    acc[O][0] = fmaxf(acc[O][0], max5(p01[0].x, p01[1].x, p01[2].x, p01[3].x, p01[4].x)); \
    acc[O][1] = fmaxf(acc[O][1], max5(p01[0].y, p01[1].y, p01[2].y, p01[3].y, p01[4].y)); \
    acc[O][2] = fmaxf(acc[O][2], max5(p23[0].x, p23[1].x, p23[2].x, p23[3].x, p23[4].x)); \
    acc[O][3] = fmaxf(acc[O][3], max5(p23[0].y, p23[1].y, p23[2].y, p23[3].y, p23[4].y)); \
  } while (0)

#pragma unroll 1
  for (int c = 0; c < Cin; ++c) {
#pragma unroll
    for (int i = 0; i < Kn; ++i) {
      const float* rowp = &xs[c][ty + i][tx * 4];
      float4 q0 = *(const float4*)(rowp);
      float4 q1 = *(const float4*)(rowp + 4);
      float4 q2 = *(const float4*)(rowp + 8);
      float win[12] = {q0.x, q0.y, q0.z, q0.w, q1.x, q1.y, q1.z, q1.w,
                       q2.x, q2.y, q2.z, q2.w};

      // window pairs, shared across the 4 output channels
      v2f a2[5], b2[5];
#pragma unroll
      for (int j = 0; j < 5; ++j) {
        a2[j].x = win[2 + j]; a2[j].y = win[3 + j];
        b2[j].x = win[4 + j]; b2[j].y = win[5 + j];
      }

      // wave-uniform duplicated pairs -> s_load_dwordx2 -> SGPR pairs
      const v2f* wdp = wdup + (c * Kn + i) * Cout * Kn;

      ACC_O(0);
      ACC_O(1);
      ACC_O(2);
      ACC_O(3);
    }
  }
#undef ACC_O

  // ---- epilogue: float4 stores, coalesced ----
  const int r = tile_r0 + ty;
  const int gc0 = tile_w0 + tx * 4;
#pragma unroll
  for (int o = 0; o < Cout; ++o) {
    float4 res = make_float4(acc[o][0], acc[o][1], acc[o][2], acc[o][3]);
    *(float4*)&out[((size_t)(b * Cout + o) * Himg + r) * Wimg + gc0] = res;
  }
}

extern "C" void kernel_launch(void* const* d_in, const int* in_sizes, int n_in,
                              void* d_out, int out_size, void* d_ws, size_t ws_size,
                              hipStream_t stream) {
  const float* x = (const float*)d_in[0];
  const float* w = (const float*)d_in[1];
  float* out = (float*)d_out;

  reorg_w<<<dim3(1), dim3(512), 0, stream>>>(w);

  dim3 grid(Wimg / TW, Himg / TH, 4);  // (8, 128, 4)
  morph<<<grid, dim3(256), 0, stream>>>(x, out);
}